// Round 11
// baseline (655.929 us; speedup 1.0000x reference)
//
#include <hip/hip_runtime.h>
#include <hip/hip_bf16.h>
#include <math.h>

#define NN 20000
#define INDIM 1536
#define HID 256
#define NE 320000
#define NEDGE (NE + NN)
#define EPSV 1e-5f
#define NEG 0.2f

typedef unsigned short ushort_b;
typedef unsigned int uint32;
typedef __bf16 bf16x8 __attribute__((ext_vector_type(8)));
typedef float f32x4 __attribute__((ext_vector_type(4)));

#define AS1(p) ((const __attribute__((address_space(1))) void*)(p))
#define AS3(p) ((__attribute__((address_space(3))) void*)(p))

__device__ inline ushort_b f2bf(float x) {
  union { float f; uint32 u; } v; v.f = x;
  uint32 r = v.u + 0x7FFFu + ((v.u >> 16) & 1u);   // RNE
  return (ushort_b)(r >> 16);
}
__device__ inline float bf2f(ushort_b h) {
  union { uint32 u; float f; } v; v.u = ((uint32)h) << 16;
  return v.f;
}
__device__ inline float u2f(uint32 u) {
  union { uint32 u; float f; } v; v.u = u; return v.f;
}
__device__ inline uint32 cvtpk_bf16(float a, float b) {
  uint32 r;
  asm("v_cvt_pk_bf16_f32 %0, %1, %2" : "=v"(r) : "v"(a), "v"(b));
  return r;   // [15:0]=bf16(a), [31:16]=bf16(b)
}
__device__ inline float4 ldbf4(const ushort_b* p) {
  ushort4 u = *(const ushort4*)p;
  float4 f;
  f.x = bf2f(u.x); f.y = bf2f(u.y); f.z = bf2f(u.z); f.w = bf2f(u.w);
  return f;
}
__device__ inline float4 us4f(ushort4 u) {
  float4 f;
  f.x = bf2f(u.x); f.y = bf2f(u.y); f.z = bf2f(u.z); f.w = bf2f(u.w);
  return f;
}

// ----------------------------------------------------------------------------
// Split-bf16 MFMA GEMM (Ootomo 3-pass: Ah*Bh + Al*Bh + Ah*Bl), fp32-accurate.
// UNCHANGED from r10 (r11 isolates gat v4).
//   DUALB=0: split-K-by-z; DUALB=1: dual-B (hops).
// BM=128, BN=128, BK=32, 4 waves; A lane-private fp32 -> VGPR; B fragment-
// major bf16 hi+lo, triple-buffered 48KB; 1 barrier/step, counted vmcnt.
// ----------------------------------------------------------------------------
template<int OUTMODE, int DUALB>
__global__ __launch_bounds__(256, 3) void gemm_mfma(
    const float* __restrict__ Af,
    const ushort_b* __restrict__ Bt0, const ushort_b* __restrict__ Bt1,
    const float* __restrict__ bias0, const float* __restrict__ bias1,
    void* __restrict__ C0, void* __restrict__ C1,
    int Mstore, int Kloop, int Kstride)
{
  __shared__ ushort_b Bs[3 * 8192];   // 3 bufs x [hi 4096 | lo 4096] elems (16KB each)
  const ushort_b* Bt;
  const float* bias;
  void* Cv;
  int kbase;
  if (DUALB) {
    Bt = blockIdx.z ? Bt1 : Bt0;
    bias = blockIdx.z ? bias1 : bias0;
    Cv = blockIdx.z ? C1 : C0;
    kbase = 0;
  } else {
    Bt = Bt0;
    bias = blockIdx.z ? bias1 : bias0;           // bias only on partial 0
    Cv = (float*)C0 + (size_t)blockIdx.z * NN * HID;
    kbase = blockIdx.z * Kloop;
  }

  int tid = threadIdx.x;
  int wave = tid >> 6, lane = tid & 63;
  int quad = lane >> 4, mrow = lane & 15;
  int r0 = blockIdx.y * 128;
  int p  = blockIdx.x;                // 128-col panel
  int nk = Kloop >> 5;
  int nchunk = Kstride >> 5;
  int cb = kbase >> 5;

  // two A rows per lane (clamped so every thread always issues 4 loads)
  int arow0 = r0 + (wave << 5) + mrow;
  int arow1 = arow0 + 16;
  if (arow0 >= Mstore) arow0 = Mstore - 1;
  if (arow1 >= Mstore) arow1 = Mstore - 1;
  const float* Aptr0 = Af + (size_t)arow0 * Kstride + kbase + (quad << 3);
  const float* Aptr1 = Af + (size_t)arow1 * Kstride + kbase + (quad << 3);

  f32x4 acc[2][8] = {};
  float pA0[16], pA1[16];             // [row0 8 | row1 8] per prefetch slot

  auto issueB = [&](int kc, int buf) {
    const char* g = (const char*)Bt + (((size_t)(p * nchunk + (cb + kc))) << 14);
    char* l = (char*)Bs + buf * 16384;
    int o = tid << 4;
#pragma unroll
    for (int pl = 0; pl < 2; pl++) {
      int off = (pl << 13) + o;
      __builtin_amdgcn_global_load_lds(AS1(g + off), AS3(l + off), 16, 0, 0);
      __builtin_amdgcn_global_load_lds(AS1(g + off + 4096), AS3(l + off + 4096), 16, 0, 0);
    }
  };
  auto loadA = [&](int k, float* dst) {
    const float* s0 = Aptr0 + (k << 5);
    const float* s1 = Aptr1 + (k << 5);
    *(float4*)(dst)      = *(const float4*)(s0);
    *(float4*)(dst + 4)  = *(const float4*)(s0 + 4);
    *(float4*)(dst + 8)  = *(const float4*)(s1);
    *(float4*)(dst + 12) = *(const float4*)(s1 + 4);
  };
  auto cvtFrag = [&](const float* s, bf16x8& hh, bf16x8& ll) {
    union { bf16x8 v; uint32 u[4]; } H, L;
#pragma unroll
    for (int q2 = 0; q2 < 4; q2++) {
      float a = s[2 * q2], b = s[2 * q2 + 1];
      uint32 hp = cvtpk_bf16(a, b);
      float fa = u2f(hp << 16);
      float fb = u2f(hp & 0xffff0000u);
      H.u[q2] = hp;
      L.u[q2] = cvtpk_bf16(a - fa, b - fb);
    }
    hh = H.v; ll = L.v;
  };
  auto computeStage = [&](int buf, const bf16x8& ah0, const bf16x8& al0,
                          const bf16x8& ah1, const bf16x8& al1) {
    const ushort_b* bp = Bs + buf * 8192;
#pragma unroll
    for (int u = 0; u < 8; u++) {
      bf16x8 bh = *(const bf16x8*)(bp + (u << 9) + (lane << 3));
      bf16x8 bl = *(const bf16x8*)(bp + 4096 + (u << 9) + (lane << 3));
      acc[0][u] = __builtin_amdgcn_mfma_f32_16x16x32_bf16(ah0, bh, acc[0][u], 0, 0, 0);
      acc[0][u] = __builtin_amdgcn_mfma_f32_16x16x32_bf16(al0, bh, acc[0][u], 0, 0, 0);
      acc[0][u] = __builtin_amdgcn_mfma_f32_16x16x32_bf16(ah0, bl, acc[0][u], 0, 0, 0);
      acc[1][u] = __builtin_amdgcn_mfma_f32_16x16x32_bf16(ah1, bh, acc[1][u], 0, 0, 0);
      acc[1][u] = __builtin_amdgcn_mfma_f32_16x16x32_bf16(al1, bh, acc[1][u], 0, 0, 0);
      acc[1][u] = __builtin_amdgcn_mfma_f32_16x16x32_bf16(ah1, bl, acc[1][u], 0, 0, 0);
    }
  };

  // ---- prologue: A0(4), B0(4), B1(4), A1(4) in flight; drain A0+B0 -> keep 8
  loadA(0, pA0);
  issueB(0, 0);
  issueB(1, 1);
  loadA(1, pA1);
  asm volatile("s_waitcnt vmcnt(8)" ::: "memory");
  __builtin_amdgcn_sched_barrier(0);
  __builtin_amdgcn_s_barrier();
  __builtin_amdgcn_sched_barrier(0);

  int bcur = 0;                       // buffer holding B(k)
  for (int k = 0; k < nk; k += 2) {
    int b1 = bcur + 1; if (b1 >= 3) b1 -= 3;
    int b2 = bcur + 2; if (b2 >= 3) b2 -= 3;

    // ---- even step k: B(k) in bcur, B(k+1) in flight into b1
    {
      bf16x8 ah0, al0, ah1, al1;
      cvtFrag(pA0, ah0, al0);
      cvtFrag(pA0 + 8, ah1, al1);                // consume A(k) before reload
      if (k + 2 < nk) { issueB(k + 2, b2); loadA(k + 2, pA0); }
      computeStage(bcur, ah0, al0, ah1, al1);
      if (k + 2 < nk) { asm volatile("s_waitcnt vmcnt(8)" ::: "memory"); }
      else            { asm volatile("s_waitcnt vmcnt(4)" ::: "memory"); }
      __builtin_amdgcn_sched_barrier(0);
      __builtin_amdgcn_s_barrier();
      __builtin_amdgcn_sched_barrier(0);
    }
    // ---- odd step k+1: B(k+1) in b1
    {
      bf16x8 ah0, al0, ah1, al1;
      cvtFrag(pA1, ah0, al0);
      cvtFrag(pA1 + 8, ah1, al1);
      if (k + 3 < nk) { issueB(k + 3, bcur); loadA(k + 3, pA1); }
      computeStage(b1, ah0, al0, ah1, al1);
      if (k + 3 < nk) {
        asm volatile("s_waitcnt vmcnt(8)" ::: "memory");
        __builtin_amdgcn_sched_barrier(0);
        __builtin_amdgcn_s_barrier();
        __builtin_amdgcn_sched_barrier(0);
      }
    }
    bcur = b2;
  }

  // ---- epilogue: D[row = t*16 + quad*4 + r][col = u*16 + mrow] per frag
#pragma unroll
  for (int u = 0; u < 8; u++) {
    int col = (p << 7) + (u << 4) + mrow;
    float bb = bias[col];
#pragma unroll
    for (int t = 0; t < 2; t++) {
#pragma unroll
      for (int r = 0; r < 4; r++) {
        int row = r0 + (wave << 5) + (t << 4) + (quad << 2) + r;
        if (row < Mstore) {
          float v = acc[t][u][r] + bb;
          if (OUTMODE == 3) v = 0.5f * v * (1.f + erff(v * 0.70710678118654752f));
          if (OUTMODE == 2) ((ushort_b*)Cv)[(size_t)row * 256 + col] = f2bf(v);
          else              ((float*)Cv)[(size_t)row * 256 + col] = v;
        }
      }
    }
  }
}

// ----------------------------------------------------------------------------
// Weight prep: W [K][256] fp32 -> fragment-major bf16 hi+lo.
// ONE fused dispatch: grid (48, 2, 8); z==7 -> proj (c 0..47),
// z<7 -> {Wl[0..2], Wr[0..2], h1_W} 256x256 (c 0..7; others early-exit).
// ----------------------------------------------------------------------------
__device__ inline void prep_body(const float* __restrict__ W, int ldw, int nchunk,
                                 ushort_b* __restrict__ out, int c, int p, int tid)
{
  ushort_b* base = out + (((size_t)(p * nchunk + c)) << 13);
#pragma unroll
  for (int g0 = 0; g0 < 2; g0++) {
    int g = tid + (g0 << 8);
    int u = g >> 6, l = g & 63;
    int quad = l >> 4, mrow = l & 15;
    int col = (p << 7) + (u << 4) + mrow;
    int krow = (c << 5) + (quad << 3);
    uint32 hu[4], lu[4];
#pragma unroll
    for (int q2 = 0; q2 < 4; q2++) {
      float a = W[(size_t)(krow + 2 * q2) * ldw + col];
      float b = W[(size_t)(krow + 2 * q2 + 1) * ldw + col];
      ushort_b h0 = f2bf(a), h1 = f2bf(b);
      hu[q2] = (uint32)h0 | ((uint32)h1 << 16);
      lu[q2] = (uint32)f2bf(a - bf2f(h0)) | ((uint32)f2bf(b - bf2f(h1)) << 16);
    }
    *(uint4*)(base + (size_t)g * 8)        = make_uint4(hu[0], hu[1], hu[2], hu[3]);
    *(uint4*)(base + 4096 + (size_t)g * 8) = make_uint4(lu[0], lu[1], lu[2], lu[3]);
  }
}

__global__ __launch_bounds__(256) void prep_all(
    const float* __restrict__ projW, const float* __restrict__ Wl,
    const float* __restrict__ Wr, const float* __restrict__ h1W,
    ushort_b* __restrict__ wtp, ushort_b* __restrict__ w7)
{
  int z = blockIdx.z, c = blockIdx.x, p = blockIdx.y;
  if (z == 7) {
    prep_body(projW, HID, INDIM / 32, wtp, c, p, threadIdx.x);
  } else {
    if (c >= 8) return;
    const float* W = (z < 3) ? Wl + (size_t)z * 65536
                   : (z < 6) ? Wr + (size_t)(z - 3) * 65536
                             : h1W;
    prep_body(W, 256, 8, w7 + (size_t)z * 131072, c, p, threadIdx.x);
  }
}

// ----------------------------------------------------------------------------
// LayerNorm over rows of 256 on sum of TWO split-K partials at in + z*NN*HID
// (bias folded into partial 0).  Writes fp32 (in-place over partial 0 safe).
// ----------------------------------------------------------------------------
__global__ __launch_bounds__(256) void ln_sum_kernel(
    const float* __restrict__ in,
    const float* __restrict__ g, const float* __restrict__ b,
    float* __restrict__ out, int n)
{
  int wave = threadIdx.x >> 6, lane = threadIdx.x & 63;
  int row = blockIdx.x * 4 + wave;
  if (row >= n) return;
  int c = lane << 2;
  const float* p0 = in + (size_t)row * HID + c;
  float4 v  = *(const float4*)(p0);
  float4 v1 = *(const float4*)(p0 + (size_t)NN * HID);
  v.x += v1.x; v.y += v1.y; v.z += v1.z; v.w += v1.w;
  float s1 = v.x + v.y + v.z + v.w;
  float s2 = v.x * v.x + v.y * v.y + v.z * v.z + v.w * v.w;
#pragma unroll
  for (int m = 1; m < 64; m <<= 1) {
    s1 += __shfl_xor(s1, m, 64);
    s2 += __shfl_xor(s2, m, 64);
  }
  float mu = s1 * (1.f / 256.f);
  float var = s2 * (1.f / 256.f) - mu * mu;
  float rstd = rsqrtf(var + EPSV);
  float4 gv = *(const float4*)(g + c);
  float4 bv = *(const float4*)(b + c);
  float4 o;
  o.x = (v.x - mu) * rstd * gv.x + bv.x;
  o.y = (v.y - mu) * rstd * gv.y + bv.y;
  o.z = (v.z - mu) * rstd * gv.z + bv.z;
  o.w = (v.w - mu) * rstd * gv.w + bv.w;
  *(float4*)(out + (size_t)row * HID + c) = o;
}

// ----------------------------------------------------------------------------
// CSR build (count also zero-inits zbias — saves a memset dispatch)
// ----------------------------------------------------------------------------
__global__ void count_kernel(const int* __restrict__ ei, int* __restrict__ cnt,
                             float* __restrict__ zbias)
{
  int e = blockIdx.x * blockDim.x + threadIdx.x;
  if (e < HID) zbias[e] = 0.f;
  if (e < NEDGE) {
    int d = (e < NE) ? ei[NE + e] : (e - NE);
    atomicAdd(&cnt[d], 1);
  }
}

__global__ __launch_bounds__(1024) void scan_kernel(
    const int* __restrict__ cnt, int* __restrict__ offs, int* __restrict__ cursor)
{
  __shared__ int sums[1024];
  int tid = threadIdx.x;
  const int CH = 20;               // 1024*20 = 20480 >= NN
  int base = tid * CH;
  int loc[CH];
  int s = 0;
#pragma unroll
  for (int i = 0; i < CH; i++) {
    int idx = base + i;
    int v = (idx < NN) ? cnt[idx] : 0;
    loc[i] = s;
    s += v;
  }
  sums[tid] = s;
  __syncthreads();
  for (int off = 1; off < 1024; off <<= 1) {
    int t = (tid >= off) ? sums[tid - off] : 0;
    __syncthreads();
    sums[tid] += t;
    __syncthreads();
  }
  int pre = (tid == 0) ? 0 : sums[tid - 1];
#pragma unroll
  for (int i = 0; i < CH; i++) {
    int idx = base + i;
    if (idx < NN) { int e = pre + loc[i]; offs[idx] = e; cursor[idx] = e; }
  }
  if (tid == 0) offs[NN] = NEDGE;
}

__global__ void scatter_kernel(const int* __restrict__ ei, int* __restrict__ cursor,
                               int* __restrict__ csr_src)
{
  int e = blockIdx.x * blockDim.x + threadIdx.x;
  if (e < NEDGE) {
    int s, d;
    if (e < NE) { s = ei[e]; d = ei[NE + e]; }
    else { s = e - NE; d = e - NE; }
    int p = atomicAdd(&cursor[d], 1);
    csr_src[p] = s;
  }
}

// ----------------------------------------------------------------------------
// GATv2 aggregation v4 (r11): width-8 groups, gathers prefetched one FULL
// group ahead (8 rows in flight/wave, slack ~600cy vs v3's ~300cy).
// DISCRIMINATING EXPERIMENT: latency-bound -> gat 84 -> ~60us; neutral ->
// bandwidth-bound at random-gather roofline (stop touching gat).
// All loops fully unrolled, compile-time indices (rule #20).
// __launch_bounds__(256,5): >= 20 waves/CU, VGPR cap 102 (est ~90).
// Grid = NN/4 blocks of 4 waves.
// ----------------------------------------------------------------------------
__device__ inline float edge_logit(float4 xv, float4 xrv, float4 attv) {
  float e0 = xv.x + xrv.x, e1 = xv.y + xrv.y, e2 = xv.z + xrv.z, e3 = xv.w + xrv.w;
  e0 = (e0 > 0.f) ? e0 : NEG * e0;
  e1 = (e1 > 0.f) ? e1 : NEG * e1;
  e2 = (e2 > 0.f) ? e2 : NEG * e2;
  e3 = (e3 > 0.f) ? e3 : NEG * e3;
  float lc = e0 * attv.x + e1 * attv.y + e2 * attv.z + e3 * attv.w;
  lc += __shfl_xor(lc, 1, 16);
  lc += __shfl_xor(lc, 2, 16);
  lc += __shfl_xor(lc, 4, 16);
  lc += __shfl_xor(lc, 8, 16);
  return lc;
}

#define ACCUM(i, wt, xv) {                             \
    lS[i] += wt;                                       \
    pS##i##0 += wt * xv.x; pS##i##1 += wt * xv.y;      \
    pS##i##2 += wt * xv.z; pS##i##3 += wt * xv.w; }

__global__ __launch_bounds__(256, 5) void gat_kernel(
    const ushort_b* __restrict__ xl, const ushort_b* __restrict__ xr,
    const float* __restrict__ x_in, const float* __restrict__ att,
    const float* __restrict__ gbias, const float* __restrict__ ln_g,
    const float* __restrict__ ln_b, const int* __restrict__ offs,
    const int* __restrict__ csr_src, float* __restrict__ x_out)
{
  int wave = threadIdx.x >> 6, lane = threadIdx.x & 63;
  int node = blockIdx.x * 4 + wave;   // NN % 4 == 0, grid = NN/4
  int c = lane << 2;
  float4 xrv = ldbf4(xr + (size_t)node * HID + c);
  float4 attv = *(const float4*)(att + c);

  float lS[4] = {0.f, 0.f, 0.f, 0.f};
  float pS00 = 0.f, pS01 = 0.f, pS02 = 0.f, pS03 = 0.f;
  float pS10 = 0.f, pS11 = 0.f, pS12 = 0.f, pS13 = 0.f;
  float pS20 = 0.f, pS21 = 0.f, pS22 = 0.f, pS23 = 0.f;
  float pS30 = 0.f, pS31 = 0.f, pS32 = 0.f, pS33 = 0.f;

  int e = offs[node], end = offs[node + 1];
  int last = end - 1;
#define CI(x) ((x) <= last ? (x) : last)
  auto G = [&](int i) { return *(const ushort4*)(xl + (size_t)i * HID + c); };

  ushort4 a[8], b[8];
  int j[8];

  // ---- prologue: group-0 indices + gathers; group-1 indices (if any)
  {
    int ji[8];
#pragma unroll
    for (int k = 0; k < 8; k++) ji[k] = csr_src[CI(e + k)];
#pragma unroll
    for (int k = 0; k < 8; k++) a[k] = G(ji[k]);
  }
  int en = e + 8;
  bool more = en < end;
  if (more) {
#pragma unroll
    for (int k = 0; k < 8; k++) j[k] = csr_src[CI(en + k)];
  }

  for (;;) {
    int rem = end - e;                // >= 1
    int en2 = en + 8;
    bool more2 = more && (en2 < end);
    if (more) {
#pragma unroll
      for (int k = 0; k < 8; k++) b[k] = G(j[k]);   // indices already resident
      if (more2) {
#pragma unroll
        for (int k = 0; k < 8; k++) j[k] = csr_src[CI(en2 + k)];
      }
    }
    // ---- compute 8 edges (k compile-time; edge k -> acc set k&3)
#pragma unroll
    for (int k = 0; k < 8; k++) {
      float4 xv = us4f(a[k]);
      float g = edge_logit(xv, xrv, attv);
      float wgt = (k == 0 || rem > k) ? __expf(g) : 0.f;
      if ((k & 3) == 0) ACCUM(0, wgt, xv);
      if ((k & 3) == 1) ACCUM(1, wgt, xv);
      if ((k & 3) == 2) ACCUM(2, wgt, xv);
      if ((k & 3) == 3) ACCUM(3, wgt, xv);
    }
    if (!more) break;
    e = en; en = en2; more = more2;
#pragma unroll
    for (int k = 0; k < 8; k++) a[k] = b[k];
  }
#undef CI

  float l  = lS[0] + lS[1] + lS[2] + lS[3];
  float q0 = pS00 + pS10 + pS20 + pS30;
  float q1 = pS01 + pS11 + pS21 + pS31;
  float q2 = pS02 + pS12 + pS22 + pS32;
  float q3 = pS03 + pS13 + pS23 + pS33;

  float inv = 1.f / l;
  float4 xv = *(const float4*)(x_in + (size_t)node * HID + c);
  float4 gb = *(const float4*)(gbias + c);
  float o0 = q0 * inv + gb.x + xv.x;
  float o1 = q1 * inv + gb.y + xv.y;
  float o2 = q2 * inv + gb.z + xv.z;
  float o3 = q3 * inv + gb.w + xv.w;
  float s1s = o0 + o1 + o2 + o3;
  float s2s = o0 * o0 + o1 * o1 + o2 * o2 + o3 * o3;
#pragma unroll
  for (int mmk = 1; mmk < 64; mmk <<= 1) {
    s1s += __shfl_xor(s1s, mmk, 64);
    s2s += __shfl_xor(s2s, mmk, 64);
  }
  float mu = s1s * (1.f / 256.f);
  float var = s2s * (1.f / 256.f) - mu * mu;
  float rstd = rsqrtf(var + EPSV);
  float4 gv = *(const float4*)(ln_g + c);
  float4 bv = *(const float4*)(ln_b + c);
  float4 o;
  o.x = (o0 - mu) * rstd * gv.x + bv.x;
  o.y = (o1 - mu) * rstd * gv.y + bv.y;
  o.z = (o2 - mu) * rstd * gv.z + bv.z;
  o.w = (o3 - mu) * rstd * gv.w + bv.w;
  *(float4*)(x_out + (size_t)node * HID + c) = o;
}

// ----------------------------------------------------------------------------
// Final head: out[N,3] = t1[N,256](fp32) @ W[256,3] + b. One wave per row.
// ----------------------------------------------------------------------------
__global__ __launch_bounds__(256) void head2_kernel(
    const float* __restrict__ t1, const float* __restrict__ W,
    const float* __restrict__ bias, float* __restrict__ out)
{
  int wave = threadIdx.x >> 6, lane = threadIdx.x & 63;
  int row = blockIdx.x * 4 + wave;
  if (row >= NN) return;
  int c = lane << 2;
  float4 v = *(const float4*)(t1 + (size_t)row * HID + c);
  float p0 = 0.f, p1 = 0.f, p2 = 0.f;
#pragma unroll
  for (int j = 0; j < 4; j++) {
    float vj = (&v.x)[j];
    p0 += vj * W[(c + j) * 3 + 0];
    p1 += vj * W[(c + j) * 3 + 1];
    p2 += vj * W[(c + j) * 3 + 2];
  }
#pragma unroll
  for (int mm = 1; mm < 64; mm <<= 1) {
    p0 += __shfl_xor(p0, mm, 64);
    p1 += __shfl_xor(p1, mm, 64);
    p2 += __shfl_xor(p2, mm, 64);
  }
  if (lane == 0) {
    out[(size_t)row * 3 + 0] = p0 + bias[0];
    out[(size_t)row * 3 + 1] = p1 + bias[1];
    out[(size_t)row * 3 + 2] = p2 + bias[2];
  }
}

// ----------------------------------------------------------------------------
extern "C" void kernel_launch(void* const* d_in, const int* in_sizes, int n_in,
                              void* d_out, int out_size, void* d_ws, size_t ws_size,
                              hipStream_t stream)
{
  const float* features = (const float*)d_in[0];
  const int*   ei       = (const int*)d_in[1];
  const float* proj_W   = (const float*)d_in[2];
  const float* proj_b   = (const float*)d_in[3];
  const float* n0_g     = (const float*)d_in[4];
  const float* n0_b     = (const float*)d_in[5];
  const float* Wl       = (const float*)d_in[6];
  const float* bl       = (const float*)d_in[7];
  const float* Wr       = (const float*)d_in[8];
  const float* br       = (const float*)d_in[9];
  const float* att      = (const float*)d_in[10];
  const float* gbias    = (const float*)d_in[11];
  const float* ln_g     = (const float*)d_in[12];
  const float* ln_b     = (const float*)d_in[13];
  const float* h1_W     = (const float*)d_in[14];
  const float* h1_b     = (const float*)d_in[15];
  const float* h2_W     = (const float*)d_in[16];
  const float* h2_b     = (const float*)d_in[17];
  float* out = (float*)d_out;

  char* w = (char*)d_ws;
  // x0, x1 are the 2 contiguous split-K partials of proj (ln_sum reads both
  // row-wise and writes x0 in-place).
  float*    x0    = (float*)w;    w += (size_t)NN * HID * 4;   // partial0 / LN'd state fp32
  float*    x1    = (float*)w;    w += (size_t)NN * HID * 4;   // partial1 / gat out
  float*    part1 = (float*)w;    w += (size_t)NN * HID * 4;   // gelu out
  ushort_b* xlb   = (ushort_b*)w; w += (size_t)NN * HID * 2;
  ushort_b* xrb   = (ushort_b*)w; w += (size_t)NN * HID * 2;
  ushort_b* wtp   = (ushort_b*)w; w += (size_t)2 * HID * INDIM * 2;  // proj frag-major hi+lo
  ushort_b* w7    = (ushort_b*)w; w += (size_t)14 * HID * HID * 2;   // 7 weights frag-major hi+lo
  float* zbias = (float*)w; w += (size_t)HID * 4;
  int* cnt     = (int*)w;  w += (size_t)NN * 4;
  int* offs    = (int*)w;  w += (size_t)(NN + 1) * 4;
  int* cursor  = (int*)w;  w += (size_t)NN * 4;
  int* csr     = (int*)w;  w += (size_t)NEDGE * 4;

  // ---- CSR build (count also zeroes zbias) + weight prep (single dispatch)
  hipMemsetAsync(cnt, 0, (size_t)NN * 4, stream);
  count_kernel<<<(NEDGE + 255) / 256, 256, 0, stream>>>(ei, cnt, zbias);
  scan_kernel<<<1, 1024, 0, stream>>>(cnt, offs, cursor);
  scatter_kernel<<<(NEDGE + 255) / 256, 256, 0, stream>>>(ei, cursor, csr);
  prep_all<<<dim3(INDIM / 32, 2, 8), 256, 0, stream>>>(proj_W, Wl, Wr, h1_W, wtp, w7);

  const int MB = (NN + 127) / 128;    // 157
  dim3 gproj(2, MB, 2);               // split-K=2
  dim3 ghop(2, MB, 2);
  dim3 gsingle(2, MB, 1);

  // ---- input projection: split-K=2, partials at x0 + z*NN*HID
  gemm_mfma<0, 0><<<gproj, 256, 0, stream>>>(
      features, wtp, wtp, proj_b, zbias, x0, x0, NN, INDIM / 2, INDIM);
  ln_sum_kernel<<<(NN + 3) / 4, 256, 0, stream>>>(x0, n0_g, n0_b, x0, NN);

  // ---- 3 GAT hops
  float* xcur = x0;
  float* xnxt = x1;
  for (int h = 0; h < 3; h++) {
    gemm_mfma<2, 1><<<ghop, 256, 0, stream>>>(
        xcur, w7 + (size_t)h * 131072, w7 + (size_t)(3 + h) * 131072,
        bl + h * HID, br + h * HID, xlb, xrb, NN, HID, HID);
    gat_kernel<<<NN / 4, 256, 0, stream>>>(
        xlb, xrb, xcur, att + h * HID, gbias + h * HID,
        ln_g + h * HID, ln_b + h * HID, offs, csr, xnxt);
    float* t = xcur; xcur = xnxt; xnxt = t;
  }

  // ---- head: h1 (GELU, fp32 out) then 256x3
  gemm_mfma<3, 1><<<gsingle, 256, 0, stream>>>(
      xcur, w7 + (size_t)6 * 131072, w7 + (size_t)6 * 131072,
      h1_b, h1_b, part1, part1, NN, HID, HID);
  head2_kernel<<<(NN + 3) / 4, 256, 0, stream>>>(part1, h2_W, h2_b, out);
}

// Round 12
// 575.480 us; speedup vs baseline: 1.1398x; 1.1398x over previous
//
#include <hip/hip_runtime.h>
#include <hip/hip_bf16.h>
#include <math.h>

#define NN 20000
#define INDIM 1536
#define HID 256
#define NE 320000
#define NEDGE (NE + NN)
#define EPSV 1e-5f
#define NEG 0.2f

typedef unsigned short ushort_b;
typedef unsigned int uint32;
typedef __bf16 bf16x8 __attribute__((ext_vector_type(8)));
typedef float f32x4 __attribute__((ext_vector_type(4)));

#define AS1(p) ((const __attribute__((address_space(1))) void*)(p))
#define AS3(p) ((__attribute__((address_space(3))) void*)(p))

__device__ inline ushort_b f2bf(float x) {
  union { float f; uint32 u; } v; v.f = x;
  uint32 r = v.u + 0x7FFFu + ((v.u >> 16) & 1u);   // RNE
  return (ushort_b)(r >> 16);
}
__device__ inline float bf2f(ushort_b h) {
  union { uint32 u; float f; } v; v.u = ((uint32)h) << 16;
  return v.f;
}
__device__ inline float u2f(uint32 u) {
  union { uint32 u; float f; } v; v.u = u; return v.f;
}
__device__ inline uint32 cvtpk_bf16(float a, float b) {
  uint32 r;
  asm("v_cvt_pk_bf16_f32 %0, %1, %2" : "=v"(r) : "v"(a), "v"(b));
  return r;   // [15:0]=bf16(a), [31:16]=bf16(b)
}
__device__ inline float4 ldbf4(const ushort_b* p) {
  ushort4 u = *(const ushort4*)p;
  float4 f;
  f.x = bf2f(u.x); f.y = bf2f(u.y); f.z = bf2f(u.z); f.w = bf2f(u.w);
  return f;
}
__device__ inline float4 us4f(ushort4 u) {
  float4 f;
  f.x = bf2f(u.x); f.y = bf2f(u.y); f.z = bf2f(u.z); f.w = bf2f(u.w);
  return f;
}

// ----------------------------------------------------------------------------
// Split-bf16 MFMA GEMM (Ootomo 3-pass: Ah*Bh + Al*Bh + Ah*Bl), fp32-accurate.
// UNCHANGED from r10 (best verified config, 578.8us).
//   DUALB=0: split-K-by-z; DUALB=1: dual-B (hops).
// BM=128, BN=128, BK=32, 4 waves; A lane-private fp32 -> VGPR; B fragment-
// major bf16 hi+lo, triple-buffered 48KB; 1 barrier/step, counted vmcnt.
// ----------------------------------------------------------------------------
template<int OUTMODE, int DUALB>
__global__ __launch_bounds__(256, 3) void gemm_mfma(
    const float* __restrict__ Af,
    const ushort_b* __restrict__ Bt0, const ushort_b* __restrict__ Bt1,
    const float* __restrict__ bias0, const float* __restrict__ bias1,
    void* __restrict__ C0, void* __restrict__ C1,
    int Mstore, int Kloop, int Kstride)
{
  __shared__ ushort_b Bs[3 * 8192];   // 3 bufs x [hi 4096 | lo 4096] elems (16KB each)
  const ushort_b* Bt;
  const float* bias;
  void* Cv;
  int kbase;
  if (DUALB) {
    Bt = blockIdx.z ? Bt1 : Bt0;
    bias = blockIdx.z ? bias1 : bias0;
    Cv = blockIdx.z ? C1 : C0;
    kbase = 0;
  } else {
    Bt = Bt0;
    bias = blockIdx.z ? bias1 : bias0;           // bias only on partial 0
    Cv = (float*)C0 + (size_t)blockIdx.z * NN * HID;
    kbase = blockIdx.z * Kloop;
  }

  int tid = threadIdx.x;
  int wave = tid >> 6, lane = tid & 63;
  int quad = lane >> 4, mrow = lane & 15;
  int r0 = blockIdx.y * 128;
  int p  = blockIdx.x;                // 128-col panel
  int nk = Kloop >> 5;
  int nchunk = Kstride >> 5;
  int cb = kbase >> 5;

  // two A rows per lane (clamped so every thread always issues 4 loads)
  int arow0 = r0 + (wave << 5) + mrow;
  int arow1 = arow0 + 16;
  if (arow0 >= Mstore) arow0 = Mstore - 1;
  if (arow1 >= Mstore) arow1 = Mstore - 1;
  const float* Aptr0 = Af + (size_t)arow0 * Kstride + kbase + (quad << 3);
  const float* Aptr1 = Af + (size_t)arow1 * Kstride + kbase + (quad << 3);

  f32x4 acc[2][8] = {};
  float pA0[16], pA1[16];             // [row0 8 | row1 8] per prefetch slot

  auto issueB = [&](int kc, int buf) {
    const char* g = (const char*)Bt + (((size_t)(p * nchunk + (cb + kc))) << 14);
    char* l = (char*)Bs + buf * 16384;
    int o = tid << 4;
#pragma unroll
    for (int pl = 0; pl < 2; pl++) {
      int off = (pl << 13) + o;
      __builtin_amdgcn_global_load_lds(AS1(g + off), AS3(l + off), 16, 0, 0);
      __builtin_amdgcn_global_load_lds(AS1(g + off + 4096), AS3(l + off + 4096), 16, 0, 0);
    }
  };
  auto loadA = [&](int k, float* dst) {
    const float* s0 = Aptr0 + (k << 5);
    const float* s1 = Aptr1 + (k << 5);
    *(float4*)(dst)      = *(const float4*)(s0);
    *(float4*)(dst + 4)  = *(const float4*)(s0 + 4);
    *(float4*)(dst + 8)  = *(const float4*)(s1);
    *(float4*)(dst + 12) = *(const float4*)(s1 + 4);
  };
  auto cvtFrag = [&](const float* s, bf16x8& hh, bf16x8& ll) {
    union { bf16x8 v; uint32 u[4]; } H, L;
#pragma unroll
    for (int q2 = 0; q2 < 4; q2++) {
      float a = s[2 * q2], b = s[2 * q2 + 1];
      uint32 hp = cvtpk_bf16(a, b);
      float fa = u2f(hp << 16);
      float fb = u2f(hp & 0xffff0000u);
      H.u[q2] = hp;
      L.u[q2] = cvtpk_bf16(a - fa, b - fb);
    }
    hh = H.v; ll = L.v;
  };
  auto computeStage = [&](int buf, const bf16x8& ah0, const bf16x8& al0,
                          const bf16x8& ah1, const bf16x8& al1) {
    const ushort_b* bp = Bs + buf * 8192;
#pragma unroll
    for (int u = 0; u < 8; u++) {
      bf16x8 bh = *(const bf16x8*)(bp + (u << 9) + (lane << 3));
      bf16x8 bl = *(const bf16x8*)(bp + 4096 + (u << 9) + (lane << 3));
      acc[0][u] = __builtin_amdgcn_mfma_f32_16x16x32_bf16(ah0, bh, acc[0][u], 0, 0, 0);
      acc[0][u] = __builtin_amdgcn_mfma_f32_16x16x32_bf16(al0, bh, acc[0][u], 0, 0, 0);
      acc[0][u] = __builtin_amdgcn_mfma_f32_16x16x32_bf16(ah0, bl, acc[0][u], 0, 0, 0);
      acc[1][u] = __builtin_amdgcn_mfma_f32_16x16x32_bf16(ah1, bh, acc[1][u], 0, 0, 0);
      acc[1][u] = __builtin_amdgcn_mfma_f32_16x16x32_bf16(al1, bh, acc[1][u], 0, 0, 0);
      acc[1][u] = __builtin_amdgcn_mfma_f32_16x16x32_bf16(ah1, bl, acc[1][u], 0, 0, 0);
    }
  };

  // ---- prologue: A0(4), B0(4), B1(4), A1(4) in flight; drain A0+B0 -> keep 8
  loadA(0, pA0);
  issueB(0, 0);
  issueB(1, 1);
  loadA(1, pA1);
  asm volatile("s_waitcnt vmcnt(8)" ::: "memory");
  __builtin_amdgcn_sched_barrier(0);
  __builtin_amdgcn_s_barrier();
  __builtin_amdgcn_sched_barrier(0);

  int bcur = 0;                       // buffer holding B(k)
  for (int k = 0; k < nk; k += 2) {
    int b1 = bcur + 1; if (b1 >= 3) b1 -= 3;
    int b2 = bcur + 2; if (b2 >= 3) b2 -= 3;

    // ---- even step k: B(k) in bcur, B(k+1) in flight into b1
    {
      bf16x8 ah0, al0, ah1, al1;
      cvtFrag(pA0, ah0, al0);
      cvtFrag(pA0 + 8, ah1, al1);                // consume A(k) before reload
      if (k + 2 < nk) { issueB(k + 2, b2); loadA(k + 2, pA0); }
      computeStage(bcur, ah0, al0, ah1, al1);
      if (k + 2 < nk) { asm volatile("s_waitcnt vmcnt(8)" ::: "memory"); }
      else            { asm volatile("s_waitcnt vmcnt(4)" ::: "memory"); }
      __builtin_amdgcn_sched_barrier(0);
      __builtin_amdgcn_s_barrier();
      __builtin_amdgcn_sched_barrier(0);
    }
    // ---- odd step k+1: B(k+1) in b1
    {
      bf16x8 ah0, al0, ah1, al1;
      cvtFrag(pA1, ah0, al0);
      cvtFrag(pA1 + 8, ah1, al1);
      if (k + 3 < nk) { issueB(k + 3, bcur); loadA(k + 3, pA1); }
      computeStage(b1, ah0, al0, ah1, al1);
      if (k + 3 < nk) {
        asm volatile("s_waitcnt vmcnt(8)" ::: "memory");
        __builtin_amdgcn_sched_barrier(0);
        __builtin_amdgcn_s_barrier();
        __builtin_amdgcn_sched_barrier(0);
      }
    }
    bcur = b2;
  }

  // ---- epilogue: D[row = t*16 + quad*4 + r][col = u*16 + mrow] per frag
#pragma unroll
  for (int u = 0; u < 8; u++) {
    int col = (p << 7) + (u << 4) + mrow;
    float bb = bias[col];
#pragma unroll
    for (int t = 0; t < 2; t++) {
#pragma unroll
      for (int r = 0; r < 4; r++) {
        int row = r0 + (wave << 5) + (t << 4) + (quad << 2) + r;
        if (row < Mstore) {
          float v = acc[t][u][r] + bb;
          if (OUTMODE == 3) v = 0.5f * v * (1.f + erff(v * 0.70710678118654752f));
          if (OUTMODE == 2) ((ushort_b*)Cv)[(size_t)row * 256 + col] = f2bf(v);
          else              ((float*)Cv)[(size_t)row * 256 + col] = v;
        }
      }
    }
  }
}

// ----------------------------------------------------------------------------
// Weight prep: W [K][256] fp32 -> fragment-major bf16 hi+lo.
// ONE fused dispatch: grid (48, 2, 8); z==7 -> proj (c 0..47) AND zeroes cnt
// (runs BEFORE count_kernel now — replaces the hipMemsetAsync dispatch);
// z<7 -> {Wl[0..2], Wr[0..2], h1_W} 256x256 (c 0..7; others early-exit).
// ----------------------------------------------------------------------------
__device__ inline void prep_body(const float* __restrict__ W, int ldw, int nchunk,
                                 ushort_b* __restrict__ out, int c, int p, int tid)
{
  ushort_b* base = out + (((size_t)(p * nchunk + c)) << 13);
#pragma unroll
  for (int g0 = 0; g0 < 2; g0++) {
    int g = tid + (g0 << 8);
    int u = g >> 6, l = g & 63;
    int quad = l >> 4, mrow = l & 15;
    int col = (p << 7) + (u << 4) + mrow;
    int krow = (c << 5) + (quad << 3);
    uint32 hu[4], lu[4];
#pragma unroll
    for (int q2 = 0; q2 < 4; q2++) {
      float a = W[(size_t)(krow + 2 * q2) * ldw + col];
      float b = W[(size_t)(krow + 2 * q2 + 1) * ldw + col];
      ushort_b h0 = f2bf(a), h1 = f2bf(b);
      hu[q2] = (uint32)h0 | ((uint32)h1 << 16);
      lu[q2] = (uint32)f2bf(a - bf2f(h0)) | ((uint32)f2bf(b - bf2f(h1)) << 16);
    }
    *(uint4*)(base + (size_t)g * 8)        = make_uint4(hu[0], hu[1], hu[2], hu[3]);
    *(uint4*)(base + 4096 + (size_t)g * 8) = make_uint4(lu[0], lu[1], lu[2], lu[3]);
  }
}

__global__ __launch_bounds__(256) void prep_all(
    const float* __restrict__ projW, const float* __restrict__ Wl,
    const float* __restrict__ Wr, const float* __restrict__ h1W,
    ushort_b* __restrict__ wtp, ushort_b* __restrict__ w7,
    int* __restrict__ cnt)
{
  int z = blockIdx.z, c = blockIdx.x, p = blockIdx.y;
  if (z == 7) {
    int lin = (c * 2 + p) * 256 + threadIdx.x;   // 0..24575 >= NN
    if (lin < NN) cnt[lin] = 0;
    prep_body(projW, HID, INDIM / 32, wtp, c, p, threadIdx.x);
  } else {
    if (c >= 8) return;
    const float* W = (z < 3) ? Wl + (size_t)z * 65536
                   : (z < 6) ? Wr + (size_t)(z - 3) * 65536
                             : h1W;
    prep_body(W, 256, 8, w7 + (size_t)z * 131072, c, p, threadIdx.x);
  }
}

// ----------------------------------------------------------------------------
// LayerNorm over rows of 256 on sum of TWO split-K partials at in + z*NN*HID
// (bias folded into partial 0).  Writes fp32 (in-place over partial 0 safe).
// ----------------------------------------------------------------------------
__global__ __launch_bounds__(256) void ln_sum_kernel(
    const float* __restrict__ in,
    const float* __restrict__ g, const float* __restrict__ b,
    float* __restrict__ out, int n)
{
  int wave = threadIdx.x >> 6, lane = threadIdx.x & 63;
  int row = blockIdx.x * 4 + wave;
  if (row >= n) return;
  int c = lane << 2;
  const float* p0 = in + (size_t)row * HID + c;
  float4 v  = *(const float4*)(p0);
  float4 v1 = *(const float4*)(p0 + (size_t)NN * HID);
  v.x += v1.x; v.y += v1.y; v.z += v1.z; v.w += v1.w;
  float s1 = v.x + v.y + v.z + v.w;
  float s2 = v.x * v.x + v.y * v.y + v.z * v.z + v.w * v.w;
#pragma unroll
  for (int m = 1; m < 64; m <<= 1) {
    s1 += __shfl_xor(s1, m, 64);
    s2 += __shfl_xor(s2, m, 64);
  }
  float mu = s1 * (1.f / 256.f);
  float var = s2 * (1.f / 256.f) - mu * mu;
  float rstd = rsqrtf(var + EPSV);
  float4 gv = *(const float4*)(g + c);
  float4 bv = *(const float4*)(b + c);
  float4 o;
  o.x = (v.x - mu) * rstd * gv.x + bv.x;
  o.y = (v.y - mu) * rstd * gv.y + bv.y;
  o.z = (v.z - mu) * rstd * gv.z + bv.z;
  o.w = (v.w - mu) * rstd * gv.w + bv.w;
  *(float4*)(out + (size_t)row * HID + c) = o;
}

// ----------------------------------------------------------------------------
// CSR build (count also zero-inits zbias; cnt zeroed by prep_all)
// ----------------------------------------------------------------------------
__global__ void count_kernel(const int* __restrict__ ei, int* __restrict__ cnt,
                             float* __restrict__ zbias)
{
  int e = blockIdx.x * blockDim.x + threadIdx.x;
  if (e < HID) zbias[e] = 0.f;
  if (e < NEDGE) {
    int d = (e < NE) ? ei[NE + e] : (e - NE);
    atomicAdd(&cnt[d], 1);
  }
}

__global__ __launch_bounds__(1024) void scan_kernel(
    const int* __restrict__ cnt, int* __restrict__ offs, int* __restrict__ cursor)
{
  __shared__ int sums[1024];
  int tid = threadIdx.x;
  const int CH = 20;               // 1024*20 = 20480 >= NN
  int base = tid * CH;
  int loc[CH];
  int s = 0;
#pragma unroll
  for (int i = 0; i < CH; i++) {
    int idx = base + i;
    int v = (idx < NN) ? cnt[idx] : 0;
    loc[i] = s;
    s += v;
  }
  sums[tid] = s;
  __syncthreads();
  for (int off = 1; off < 1024; off <<= 1) {
    int t = (tid >= off) ? sums[tid - off] : 0;
    __syncthreads();
    sums[tid] += t;
    __syncthreads();
  }
  int pre = (tid == 0) ? 0 : sums[tid - 1];
#pragma unroll
  for (int i = 0; i < CH; i++) {
    int idx = base + i;
    if (idx < NN) { int e = pre + loc[i]; offs[idx] = e; cursor[idx] = e; }
  }
  if (tid == 0) offs[NN] = NEDGE;
}

__global__ void scatter_kernel(const int* __restrict__ ei, int* __restrict__ cursor,
                               int* __restrict__ csr_src)
{
  int e = blockIdx.x * blockDim.x + threadIdx.x;
  if (e < NEDGE) {
    int s, d;
    if (e < NE) { s = ei[e]; d = ei[NE + e]; }
    else { s = e - NE; d = e - NE; }
    int p = atomicAdd(&cursor[d], 1);
    csr_src[p] = s;
  }
}

// ----------------------------------------------------------------------------
// GATv2 aggregation v3 (REVERTED to r10's best: width-4, 2-level pipeline).
// r11's width-8 regressed +26us/dispatch (padded gather traffic + register
// pressure) -> gat is traffic/pattern-bound; v3 is the empirical optimum.
// Grid = NN/4 blocks of 4 waves.
// ----------------------------------------------------------------------------
__device__ inline float edge_logit(float4 xv, float4 xrv, float4 attv) {
  float e0 = xv.x + xrv.x, e1 = xv.y + xrv.y, e2 = xv.z + xrv.z, e3 = xv.w + xrv.w;
  e0 = (e0 > 0.f) ? e0 : NEG * e0;
  e1 = (e1 > 0.f) ? e1 : NEG * e1;
  e2 = (e2 > 0.f) ? e2 : NEG * e2;
  e3 = (e3 > 0.f) ? e3 : NEG * e3;
  float lc = e0 * attv.x + e1 * attv.y + e2 * attv.z + e3 * attv.w;
  lc += __shfl_xor(lc, 1, 16);
  lc += __shfl_xor(lc, 2, 16);
  lc += __shfl_xor(lc, 4, 16);
  lc += __shfl_xor(lc, 8, 16);
  return lc;
}

#define ACCUM(i, wt, xv) {                             \
    lS[i] += wt;                                       \
    pS##i##0 += wt * xv.x; pS##i##1 += wt * xv.y;      \
    pS##i##2 += wt * xv.z; pS##i##3 += wt * xv.w; }

__global__ __launch_bounds__(256, 6) void gat_kernel(
    const ushort_b* __restrict__ xl, const ushort_b* __restrict__ xr,
    const float* __restrict__ x_in, const float* __restrict__ att,
    const float* __restrict__ gbias, const float* __restrict__ ln_g,
    const float* __restrict__ ln_b, const int* __restrict__ offs,
    const int* __restrict__ csr_src, float* __restrict__ x_out)
{
  int wave = threadIdx.x >> 6, lane = threadIdx.x & 63;
  int node = blockIdx.x * 4 + wave;   // NN % 4 == 0, grid = NN/4
  int c = lane << 2;
  float4 xrv = ldbf4(xr + (size_t)node * HID + c);
  float4 attv = *(const float4*)(att + c);

  float lS[4] = {0.f, 0.f, 0.f, 0.f};
  float pS00 = 0.f, pS01 = 0.f, pS02 = 0.f, pS03 = 0.f;
  float pS10 = 0.f, pS11 = 0.f, pS12 = 0.f, pS13 = 0.f;
  float pS20 = 0.f, pS21 = 0.f, pS22 = 0.f, pS23 = 0.f;
  float pS30 = 0.f, pS31 = 0.f, pS32 = 0.f, pS33 = 0.f;

  int e = offs[node], end = offs[node + 1];
  int last = end - 1;
#define CI(x) ((x) <= last ? (x) : last)
  auto G = [&](int i) { return *(const ushort4*)(xl + (size_t)i * HID + c); };

  // ---- prologue: group-0 indices + gathers; group-1 indices (if any)
  int i0 = csr_src[e], i1 = csr_src[CI(e + 1)];
  int i2 = csr_src[CI(e + 2)], i3 = csr_src[CI(e + 3)];
  ushort4 a0 = G(i0), a1 = G(i1), a2 = G(i2), a3 = G(i3);
  int en = e + 4;
  bool more = en < end;
  int j0, j1, j2, j3;
  if (more) {
    j0 = csr_src[en]; j1 = csr_src[CI(en + 1)];
    j2 = csr_src[CI(en + 2)]; j3 = csr_src[CI(en + 3)];
  }

  for (;;) {
    int rem = end - e;                // >= 1
    int en2 = en + 4;
    bool more2 = more && (en2 < end);
    ushort4 b0, b1, b2, b3;
    if (more) {
      b0 = G(j0); b1 = G(j1); b2 = G(j2); b3 = G(j3);   // indices already resident
      if (more2) {
        j0 = csr_src[en2]; j1 = csr_src[CI(en2 + 1)];
        j2 = csr_src[CI(en2 + 2)]; j3 = csr_src[CI(en2 + 3)];
      }
    }
    float4 x0v = us4f(a0);
    float4 x1v = us4f(a1);
    float4 x2v = us4f(a2);
    float4 x3v = us4f(a3);
    float g0 = edge_logit(x0v, xrv, attv);
    float g1 = edge_logit(x1v, xrv, attv);
    float g2 = edge_logit(x2v, xrv, attv);
    float g3 = edge_logit(x3v, xrv, attv);
    float w0 = __expf(g0);                       // j=0 always valid
    float w1 = (rem > 1) ? __expf(g1) : 0.f;
    float w2 = (rem > 2) ? __expf(g2) : 0.f;
    float w3 = (rem > 3) ? __expf(g3) : 0.f;
    ACCUM(0, w0, x0v);
    ACCUM(1, w1, x1v);
    ACCUM(2, w2, x2v);
    ACCUM(3, w3, x3v);
    if (!more) break;
    e = en; en = en2; more = more2;
    a0 = b0; a1 = b1; a2 = b2; a3 = b3;
  }
#undef CI

  float l  = lS[0] + lS[1] + lS[2] + lS[3];
  float q0 = pS00 + pS10 + pS20 + pS30;
  float q1 = pS01 + pS11 + pS21 + pS31;
  float q2 = pS02 + pS12 + pS22 + pS32;
  float q3 = pS03 + pS13 + pS23 + pS33;

  float inv = 1.f / l;
  float4 xv = *(const float4*)(x_in + (size_t)node * HID + c);
  float4 gb = *(const float4*)(gbias + c);
  float o0 = q0 * inv + gb.x + xv.x;
  float o1 = q1 * inv + gb.y + xv.y;
  float o2 = q2 * inv + gb.z + xv.z;
  float o3 = q3 * inv + gb.w + xv.w;
  float s1s = o0 + o1 + o2 + o3;
  float s2s = o0 * o0 + o1 * o1 + o2 * o2 + o3 * o3;
#pragma unroll
  for (int mmk = 1; mmk < 64; mmk <<= 1) {
    s1s += __shfl_xor(s1s, mmk, 64);
    s2s += __shfl_xor(s2s, mmk, 64);
  }
  float mu = s1s * (1.f / 256.f);
  float var = s2s * (1.f / 256.f) - mu * mu;
  float rstd = rsqrtf(var + EPSV);
  float4 gv = *(const float4*)(ln_g + c);
  float4 bv = *(const float4*)(ln_b + c);
  float4 o;
  o.x = (o0 - mu) * rstd * gv.x + bv.x;
  o.y = (o1 - mu) * rstd * gv.y + bv.y;
  o.z = (o2 - mu) * rstd * gv.z + bv.z;
  o.w = (o3 - mu) * rstd * gv.w + bv.w;
  *(float4*)(x_out + (size_t)node * HID + c) = o;
}

// ----------------------------------------------------------------------------
// Final head: out[N,3] = t1[N,256](fp32) @ W[256,3] + b. One wave per row.
// ----------------------------------------------------------------------------
__global__ __launch_bounds__(256) void head2_kernel(
    const float* __restrict__ t1, const float* __restrict__ W,
    const float* __restrict__ bias, float* __restrict__ out)
{
  int wave = threadIdx.x >> 6, lane = threadIdx.x & 63;
  int row = blockIdx.x * 4 + wave;
  if (row >= NN) return;
  int c = lane << 2;
  float4 v = *(const float4*)(t1 + (size_t)row * HID + c);
  float p0 = 0.f, p1 = 0.f, p2 = 0.f;
#pragma unroll
  for (int j = 0; j < 4; j++) {
    float vj = (&v.x)[j];
    p0 += vj * W[(c + j) * 3 + 0];
    p1 += vj * W[(c + j) * 3 + 1];
    p2 += vj * W[(c + j) * 3 + 2];
  }
#pragma unroll
  for (int mm = 1; mm < 64; mm <<= 1) {
    p0 += __shfl_xor(p0, mm, 64);
    p1 += __shfl_xor(p1, mm, 64);
    p2 += __shfl_xor(p2, mm, 64);
  }
  if (lane == 0) {
    out[(size_t)row * 3 + 0] = p0 + bias[0];
    out[(size_t)row * 3 + 1] = p1 + bias[1];
    out[(size_t)row * 3 + 2] = p2 + bias[2];
  }
}

// ----------------------------------------------------------------------------
extern "C" void kernel_launch(void* const* d_in, const int* in_sizes, int n_in,
                              void* d_out, int out_size, void* d_ws, size_t ws_size,
                              hipStream_t stream)
{
  const float* features = (const float*)d_in[0];
  const int*   ei       = (const int*)d_in[1];
  const float* proj_W   = (const float*)d_in[2];
  const float* proj_b   = (const float*)d_in[3];
  const float* n0_g     = (const float*)d_in[4];
  const float* n0_b     = (const float*)d_in[5];
  const float* Wl       = (const float*)d_in[6];
  const float* bl       = (const float*)d_in[7];
  const float* Wr       = (const float*)d_in[8];
  const float* br       = (const float*)d_in[9];
  const float* att      = (const float*)d_in[10];
  const float* gbias    = (const float*)d_in[11];
  const float* ln_g     = (const float*)d_in[12];
  const float* ln_b     = (const float*)d_in[13];
  const float* h1_W     = (const float*)d_in[14];
  const float* h1_b     = (const float*)d_in[15];
  const float* h2_W     = (const float*)d_in[16];
  const float* h2_b     = (const float*)d_in[17];
  float* out = (float*)d_out;

  char* w = (char*)d_ws;
  // x0, x1 are the 2 contiguous split-K partials of proj (ln_sum reads both
  // row-wise and writes x0 in-place).
  float*    x0    = (float*)w;    w += (size_t)NN * HID * 4;   // partial0 / LN'd state fp32
  float*    x1    = (float*)w;    w += (size_t)NN * HID * 4;   // partial1 / gat out
  float*    part1 = (float*)w;    w += (size_t)NN * HID * 4;   // gelu out
  ushort_b* xlb   = (ushort_b*)w; w += (size_t)NN * HID * 2;
  ushort_b* xrb   = (ushort_b*)w; w += (size_t)NN * HID * 2;
  ushort_b* wtp   = (ushort_b*)w; w += (size_t)2 * HID * INDIM * 2;  // proj frag-major hi+lo
  ushort_b* w7    = (ushort_b*)w; w += (size_t)14 * HID * HID * 2;   // 7 weights frag-major hi+lo
  float* zbias = (float*)w; w += (size_t)HID * 4;
  int* cnt     = (int*)w;  w += (size_t)NN * 4;
  int* offs    = (int*)w;  w += (size_t)(NN + 1) * 4;
  int* cursor  = (int*)w;  w += (size_t)NN * 4;
  int* csr     = (int*)w;  w += (size_t)NEDGE * 4;

  // ---- weight prep (also zeroes cnt) + CSR build (count zeroes zbias)
  prep_all<<<dim3(INDIM / 32, 2, 8), 256, 0, stream>>>(proj_W, Wl, Wr, h1_W, wtp, w7, cnt);
  count_kernel<<<(NEDGE + 255) / 256, 256, 0, stream>>>(ei, cnt, zbias);
  scan_kernel<<<1, 1024, 0, stream>>>(cnt, offs, cursor);
  scatter_kernel<<<(NEDGE + 255) / 256, 256, 0, stream>>>(ei, cursor, csr);

  const int MB = (NN + 127) / 128;    // 157
  dim3 gproj(2, MB, 2);               // split-K=2
  dim3 ghop(2, MB, 2);
  dim3 gsingle(2, MB, 1);

  // ---- input projection: split-K=2, partials at x0 + z*NN*HID
  gemm_mfma<0, 0><<<gproj, 256, 0, stream>>>(
      features, wtp, wtp, proj_b, zbias, x0, x0, NN, INDIM / 2, INDIM);
  ln_sum_kernel<<<(NN + 3) / 4, 256, 0, stream>>>(x0, n0_g, n0_b, x0, NN);

  // ---- 3 GAT hops
  float* xcur = x0;
  float* xnxt = x1;
  for (int h = 0; h < 3; h++) {
    gemm_mfma<2, 1><<<ghop, 256, 0, stream>>>(
        xcur, w7 + (size_t)h * 131072, w7 + (size_t)(3 + h) * 131072,
        bl + h * HID, br + h * HID, xlb, xrb, NN, HID, HID);
    gat_kernel<<<NN / 4, 256, 0, stream>>>(
        xlb, xrb, xcur, att + h * HID, gbias + h * HID,
        ln_g + h * HID, ln_b + h * HID, offs, csr, xnxt);
    float* t = xcur; xcur = xnxt; xnxt = t;
  }

  // ---- head: h1 (GELU, fp32 out) then 256x3
  gemm_mfma<3, 1><<<gsingle, 256, 0, stream>>>(
      xcur, w7 + (size_t)6 * 131072, w7 + (size_t)6 * 131072,
      h1_b, h1_b, part1, part1, NN, HID, HID);
  head2_kernel<<<(NN + 3) / 4, 256, 0, stream>>>(part1, h2_W, h2_b, out);
}